// Round 1
// baseline (11352.853 us; speedup 1.0000x reference)
//
#include <hip/hip_runtime.h>

// ---------------------------------------------------------------------------
// SPADE-style encoder, fp32 baseline.
// input (8,3,256,256) -> conv0(reflect) -> IN+LReLU -> conv s2 -> IN+LReLU
// -> conv s2 -> IN+LReLU -> convT(x2 up) -> IN+LReLU -> conv3(reflect)+tanh
// -> segmap-region average pool -> out (8,19,512)
// ---------------------------------------------------------------------------

#define B 8

// ---------------- conv0: 3->32, reflect pad 1, 256x256 ----------------
__global__ __launch_bounds__(256) void conv0_kernel(
    const float* __restrict__ in, const float* __restrict__ w,
    const float* __restrict__ bias, float* __restrict__ out) {
  __shared__ float sw[32 * 27 + 32];
  for (int i = threadIdx.x; i < 32 * 27; i += 256) sw[i] = w[i];
  if (threadIdx.x < 32) sw[32 * 27 + threadIdx.x] = bias[threadIdx.x];
  __syncthreads();
  const int b = blockIdx.y;
  const int p = blockIdx.x * 256 + threadIdx.x;
  const int y = p >> 8, x = p & 255;
  const float* inb = in + (size_t)b * 3 * 65536;
  float v[27];
#pragma unroll
  for (int c = 0; c < 3; ++c) {
#pragma unroll
    for (int ky = 0; ky < 3; ++ky) {
      int iy = y + ky - 1;
      iy = iy < 0 ? -iy : (iy > 255 ? 510 - iy : iy);
#pragma unroll
      for (int kx = 0; kx < 3; ++kx) {
        int ix = x + kx - 1;
        ix = ix < 0 ? -ix : (ix > 255 ? 510 - ix : ix);
        v[c * 9 + ky * 3 + kx] = inb[c * 65536 + iy * 256 + ix];
      }
    }
  }
  float* ob = out + (size_t)b * 32 * 65536 + p;
#pragma unroll
  for (int co = 0; co < 32; ++co) {
    float a = sw[32 * 27 + co];
#pragma unroll
    for (int k = 0; k < 27; ++k) a = fmaf(v[k], sw[co * 27 + k], a);
    ob[(size_t)co * 65536] = a;
  }
}

// ---------------- fused instance-norm + leaky relu (in place) ----------------
__global__ __launch_bounds__(256) void inorm_lrelu_kernel(float* __restrict__ x,
                                                          int HW) {
  const size_t base = (size_t)blockIdx.x * HW;
  float4* p = (float4*)(x + base);
  const int n4 = HW >> 2;
  float s = 0.f, q = 0.f;
  for (int i = threadIdx.x; i < n4; i += 256) {
    float4 v = p[i];
    s += (v.x + v.y) + (v.z + v.w);
    q += (v.x * v.x + v.y * v.y) + (v.z * v.z + v.w * v.w);
  }
  __shared__ float rs[256], rq[256];
  rs[threadIdx.x] = s;
  rq[threadIdx.x] = q;
  __syncthreads();
  for (int st = 128; st > 0; st >>= 1) {
    if (threadIdx.x < st) {
      rs[threadIdx.x] += rs[threadIdx.x + st];
      rq[threadIdx.x] += rq[threadIdx.x + st];
    }
    __syncthreads();
  }
  const float m = rs[0] / (float)HW;
  float var = rq[0] / (float)HW - m * m;
  var = var < 0.f ? 0.f : var;
  const float r = rsqrtf(var + 1e-5f);
  for (int i = threadIdx.x; i < n4; i += 256) {
    float4 v = p[i];
    v.x = (v.x - m) * r; v.x = v.x >= 0.f ? v.x : 0.2f * v.x;
    v.y = (v.y - m) * r; v.y = v.y >= 0.f ? v.y : 0.2f * v.y;
    v.z = (v.z - m) * r; v.z = v.z >= 0.f ? v.z : 0.2f * v.z;
    v.w = (v.w - m) * r; v.w = v.w >= 0.f ? v.w : 0.2f * v.w;
    p[i] = v;
  }
}

// ---------------- 3x3 stride-2 zero-pad-1 conv, 32 co per block ----------------
template <int CIN, int COUT, int HIN>
__global__ __launch_bounds__(256) void conv_s2_kernel(
    const float* __restrict__ in, const float* __restrict__ w,
    const float* __restrict__ bias, float* __restrict__ out) {
  constexpr int HOUT = HIN / 2;
  const int b = blockIdx.z;
  const int co0 = blockIdx.y * 32;
  const int p = blockIdx.x * 256 + threadIdx.x;
  const int oy = p / HOUT, ox = p % HOUT;
  float acc[32];
#pragma unroll
  for (int i = 0; i < 32; ++i) acc[i] = bias[co0 + i];
  const float* inb = in + (size_t)b * CIN * HIN * HIN;
  const int iy0 = 2 * oy - 1, ix0 = 2 * ox - 1;
  for (int ci = 0; ci < CIN; ++ci) {
    float v[9];
    const float* ip = inb + (size_t)ci * HIN * HIN;
#pragma unroll
    for (int ky = 0; ky < 3; ++ky) {
      const int iy = iy0 + ky;
      const bool yok = (unsigned)iy < (unsigned)HIN;
#pragma unroll
      for (int kx = 0; kx < 3; ++kx) {
        const int ix = ix0 + kx;
        const bool ok = yok && ((unsigned)ix < (unsigned)HIN);
        v[ky * 3 + kx] = ok ? ip[iy * HIN + ix] : 0.f;
      }
    }
    const float* wp = w + ((size_t)co0 * CIN + ci) * 9;
#pragma unroll
    for (int co = 0; co < 32; ++co) {
#pragma unroll
      for (int k = 0; k < 9; ++k)
        acc[co] = fmaf(v[k], wp[(size_t)co * CIN * 9 + k], acc[co]);
    }
  }
  float* ob = out + ((size_t)b * COUT + co0) * HOUT * HOUT + p;
#pragma unroll
  for (int co = 0; co < 32; ++co) ob[(size_t)co * HOUT * HOUT] = acc[co];
}

// ---------------- transposed conv 128->256, 64x64 -> 128x128 ----------------
// lhs_dilation=2, pad ((1,2),(1,2)), k=3. Split by output parity class.
__global__ __launch_bounds__(256) void convt_kernel(
    const float* __restrict__ in, const float* __restrict__ w,
    const float* __restrict__ bias, float* __restrict__ out) {
  const int bz = blockIdx.z;
  const int b = bz >> 2;
  const int py = bz & 1, px = (bz >> 1) & 1;
  const int co0 = blockIdx.y * 32;
  const int p = blockIdx.x * 256 + threadIdx.x;  // 0..4095
  const int sy = p >> 6, sx = p & 63;
  const int oy = 2 * sy + py, ox = 2 * sx + px;
  // taps: even coord -> single tap k=1 at i=s; odd -> k=0 at i=s, k=2 at i=s+1
  const int kyA = py ? 0 : 1;
  const int kxA = px ? 0 : 1;
  const bool hasYB = py && (sy + 1 < 64);
  const bool hasXB = px && (sx + 1 < 64);
  const int kAA = kyA * 3 + kxA;
  const int kAB = kyA * 3 + 2;
  const int kBA = 6 + kxA;
  float acc[32];
#pragma unroll
  for (int i = 0; i < 32; ++i) acc[i] = bias[co0 + i];
  const float* inb = in + (size_t)b * 128 * 4096;
  for (int ci = 0; ci < 128; ++ci) {
    const float* ip = inb + ci * 4096;
    const float* wp = w + ((size_t)co0 * 128 + ci) * 9;
    const float vAA = ip[sy * 64 + sx];
    const float vAB = hasXB ? ip[sy * 64 + sx + 1] : 0.f;
    const float vBA = hasYB ? ip[(sy + 1) * 64 + sx] : 0.f;
    const float vBB = (hasYB && hasXB) ? ip[(sy + 1) * 64 + sx + 1] : 0.f;
#pragma unroll
    for (int co = 0; co < 32; ++co) {
      const float* wc = wp + (size_t)co * 128 * 9;
      acc[co] = fmaf(vAA, wc[kAA], acc[co]);
      if (px) acc[co] = fmaf(vAB, wc[kAB], acc[co]);
      if (py) acc[co] = fmaf(vBA, wc[kBA], acc[co]);
      if (py && px) acc[co] = fmaf(vBB, wc[8], acc[co]);
    }
  }
  float* ob = out + ((size_t)b * 256 + co0) * 16384;
#pragma unroll
  for (int co = 0; co < 32; ++co)
    ob[(size_t)co * 16384 + oy * 128 + ox] = acc[co];
}

// ---------------- label extraction + counts from one-hot segmap ----------------
__global__ __launch_bounds__(256) void label_kernel(
    const float* __restrict__ segmap, int* __restrict__ labels,
    float* __restrict__ cnt) {
  const int b = blockIdx.y;
  const int p = blockIdx.x * 256 + threadIdx.x;  // 0..16383
  const int i = p >> 7, j = p & 127;
  const float* sp = segmap + (size_t)b * 19 * 65536 + (2 * i) * 256 + 2 * j;
  int lab = 0;
#pragma unroll
  for (int s = 0; s < 19; ++s)
    if (sp[(size_t)s * 65536] != 0.f) lab = s;
  labels[b * 16384 + p] = lab;
  atomicAdd(&cnt[b * 19 + lab], 1.0f);
}

// ---------------- conv3 (reflect, 256->512) + tanh + region pool ----------------
__global__ __launch_bounds__(256) void conv3_pool_kernel(
    const float* __restrict__ x, const float* __restrict__ w,
    const float* __restrict__ bias, const int* __restrict__ labels,
    float* __restrict__ sums) {
  const int b = blockIdx.z;
  const int co0 = blockIdx.y * 32;
  const int p = blockIdx.x * 256 + threadIdx.x;
  const int y = p >> 7, xx = p & 127;
  __shared__ float lsum[19 * 32];
  for (int i = threadIdx.x; i < 19 * 32; i += 256) lsum[i] = 0.f;
  __syncthreads();
  float acc[32];
#pragma unroll
  for (int i = 0; i < 32; ++i) acc[i] = bias[co0 + i];
  const float* xb = x + (size_t)b * 256 * 16384;
  for (int ci = 0; ci < 256; ++ci) {
    float v[9];
    const float* ip = xb + ci * 16384;
#pragma unroll
    for (int ky = 0; ky < 3; ++ky) {
      int iy = y + ky - 1;
      iy = iy < 0 ? 1 : (iy > 127 ? 126 : iy);
#pragma unroll
      for (int kx = 0; kx < 3; ++kx) {
        int ix = xx + kx - 1;
        ix = ix < 0 ? 1 : (ix > 127 ? 126 : ix);
        v[ky * 3 + kx] = ip[iy * 128 + ix];
      }
    }
    const float* wp = w + ((size_t)co0 * 256 + ci) * 9;
#pragma unroll
    for (int co = 0; co < 32; ++co) {
#pragma unroll
      for (int k = 0; k < 9; ++k)
        acc[co] = fmaf(v[k], wp[(size_t)co * 256 * 9 + k], acc[co]);
    }
  }
  const int lab = labels[b * 16384 + p];
#pragma unroll
  for (int co = 0; co < 32; ++co) atomicAdd(&lsum[lab * 32 + co], tanhf(acc[co]));
  __syncthreads();
  for (int i = threadIdx.x; i < 19 * 32; i += 256) {
    const int s = i >> 5, co = i & 31;
    const float v = lsum[i];
    if (v != 0.f)
      atomicAdd(&sums[((size_t)b * 19 + s) * 512 + co0 + co], v);
  }
}

// ---------------- finalize: out = cnt>0 ? sums/max(cnt,1) : 0 ----------------
__global__ __launch_bounds__(256) void finalize_kernel(
    const float* __restrict__ sums, const float* __restrict__ cnt,
    float* __restrict__ out) {
  const int i = blockIdx.x * 256 + threadIdx.x;
  if (i >= B * 19 * 512) return;
  const int bs = i >> 9;
  const float c = cnt[bs];
  out[i] = c > 0.f ? sums[i] / fmaxf(c, 1.f) : 0.f;
}

// ---------------------------------------------------------------------------
extern "C" void kernel_launch(void* const* d_in, const int* in_sizes, int n_in,
                              void* d_out, int out_size, void* d_ws,
                              size_t ws_size, hipStream_t stream) {
  const float* input = (const float*)d_in[0];
  const float* segmap = (const float*)d_in[1];
  const float* w0 = (const float*)d_in[2];
  const float* b0 = (const float*)d_in[3];
  const float* w1 = (const float*)d_in[4];
  const float* b1 = (const float*)d_in[5];
  const float* w2 = (const float*)d_in[6];
  const float* b2 = (const float*)d_in[7];
  const float* wt = (const float*)d_in[8];
  const float* bt = (const float*)d_in[9];
  const float* w3 = (const float*)d_in[10];
  const float* b3 = (const float*)d_in[11];
  float* out = (float*)d_out;

  float* ws = (float*)d_ws;
  float* x0 = ws;                   // 8*32*256*256  = 16777216
  float* x1 = x0 + 16777216;        // 8*64*128*128  =  8388608
  float* x2 = x1 + 8388608;         // 8*128*64*64   =  4194304
  float* xt = x2 + 4194304;         // 8*256*128*128 = 33554432
  float* sums = xt + 33554432;      // 8*19*512      =    77824
  float* cnt = sums + 77824;        // 8*19          =      152
  int* labels = (int*)(cnt + 152);  // 8*128*128     =   131072

  hipMemsetAsync(sums, 0, (77824 + 152) * sizeof(float), stream);

  conv0_kernel<<<dim3(256, B), 256, 0, stream>>>(input, w0, b0, x0);
  inorm_lrelu_kernel<<<dim3(B * 32), 256, 0, stream>>>(x0, 65536);
  conv_s2_kernel<32, 64, 256><<<dim3(64, 2, B), 256, 0, stream>>>(x0, w1, b1, x1);
  inorm_lrelu_kernel<<<dim3(B * 64), 256, 0, stream>>>(x1, 16384);
  conv_s2_kernel<64, 128, 128><<<dim3(16, 4, B), 256, 0, stream>>>(x1, w2, b2, x2);
  inorm_lrelu_kernel<<<dim3(B * 128), 256, 0, stream>>>(x2, 4096);
  convt_kernel<<<dim3(16, 8, B * 4), 256, 0, stream>>>(x2, wt, bt, xt);
  inorm_lrelu_kernel<<<dim3(B * 256), 256, 0, stream>>>(xt, 16384);
  label_kernel<<<dim3(64, B), 256, 0, stream>>>(segmap, labels, cnt);
  conv3_pool_kernel<<<dim3(64, 16, B), 256, 0, stream>>>(xt, w3, b3, labels, sums);
  finalize_kernel<<<dim3((B * 19 * 512 + 255) / 256), 256, 0, stream>>>(sums, cnt, out);
}

// Round 2
// 5164.605 us; speedup vs baseline: 2.1982x; 2.1982x over previous
//
#include <hip/hip_runtime.h>

// ---------------------------------------------------------------------------
// SPADE-style encoder. conv3 (87% of FLOPs) now bf16 MFMA implicit-GEMM with
// fused tanh + segmap region pooling. Everything else still fp32 vector.
// ---------------------------------------------------------------------------

#define B 8

typedef __attribute__((ext_vector_type(8))) short short8;
typedef __attribute__((ext_vector_type(4))) float f32x4;

static __device__ __forceinline__ unsigned short f2bf(float f) {
  union { float f; unsigned u; } v;
  v.f = f;
  unsigned r = v.u + 0x7fffu + ((v.u >> 16) & 1u);
  return (unsigned short)(r >> 16);
}

// ---------------- conv0: 3->32, reflect pad 1, 256x256 ----------------
__global__ __launch_bounds__(256) void conv0_kernel(
    const float* __restrict__ in, const float* __restrict__ w,
    const float* __restrict__ bias, float* __restrict__ out) {
  __shared__ float sw[32 * 27 + 32];
  for (int i = threadIdx.x; i < 32 * 27; i += 256) sw[i] = w[i];
  if (threadIdx.x < 32) sw[32 * 27 + threadIdx.x] = bias[threadIdx.x];
  __syncthreads();
  const int b = blockIdx.y;
  const int p = blockIdx.x * 256 + threadIdx.x;
  const int y = p >> 8, x = p & 255;
  const float* inb = in + (size_t)b * 3 * 65536;
  float v[27];
#pragma unroll
  for (int c = 0; c < 3; ++c) {
#pragma unroll
    for (int ky = 0; ky < 3; ++ky) {
      int iy = y + ky - 1;
      iy = iy < 0 ? -iy : (iy > 255 ? 510 - iy : iy);
#pragma unroll
      for (int kx = 0; kx < 3; ++kx) {
        int ix = x + kx - 1;
        ix = ix < 0 ? -ix : (ix > 255 ? 510 - ix : ix);
        v[c * 9 + ky * 3 + kx] = inb[c * 65536 + iy * 256 + ix];
      }
    }
  }
  float* ob = out + (size_t)b * 32 * 65536 + p;
#pragma unroll
  for (int co = 0; co < 32; ++co) {
    float a = sw[32 * 27 + co];
#pragma unroll
    for (int k = 0; k < 27; ++k) a = fmaf(v[k], sw[co * 27 + k], a);
    ob[(size_t)co * 65536] = a;
  }
}

// ---------------- fused instance-norm + leaky relu (in place) ----------------
__global__ __launch_bounds__(256) void inorm_lrelu_kernel(float* __restrict__ x,
                                                          int HW) {
  const size_t base = (size_t)blockIdx.x * HW;
  float4* p = (float4*)(x + base);
  const int n4 = HW >> 2;
  float s = 0.f, q = 0.f;
  for (int i = threadIdx.x; i < n4; i += 256) {
    float4 v = p[i];
    s += (v.x + v.y) + (v.z + v.w);
    q += (v.x * v.x + v.y * v.y) + (v.z * v.z + v.w * v.w);
  }
  __shared__ float rs[256], rq[256];
  rs[threadIdx.x] = s;
  rq[threadIdx.x] = q;
  __syncthreads();
  for (int st = 128; st > 0; st >>= 1) {
    if (threadIdx.x < st) {
      rs[threadIdx.x] += rs[threadIdx.x + st];
      rq[threadIdx.x] += rq[threadIdx.x + st];
    }
    __syncthreads();
  }
  const float m = rs[0] / (float)HW;
  float var = rq[0] / (float)HW - m * m;
  var = var < 0.f ? 0.f : var;
  const float r = rsqrtf(var + 1e-5f);
  for (int i = threadIdx.x; i < n4; i += 256) {
    float4 v = p[i];
    v.x = (v.x - m) * r; v.x = v.x >= 0.f ? v.x : 0.2f * v.x;
    v.y = (v.y - m) * r; v.y = v.y >= 0.f ? v.y : 0.2f * v.y;
    v.z = (v.z - m) * r; v.z = v.z >= 0.f ? v.z : 0.2f * v.z;
    v.w = (v.w - m) * r; v.w = v.w >= 0.f ? v.w : 0.2f * v.w;
    p[i] = v;
  }
}

// ---------------- 3x3 stride-2 zero-pad-1 conv, 32 co per block ----------------
template <int CIN, int COUT, int HIN>
__global__ __launch_bounds__(256) void conv_s2_kernel(
    const float* __restrict__ in, const float* __restrict__ w,
    const float* __restrict__ bias, float* __restrict__ out) {
  constexpr int HOUT = HIN / 2;
  const int b = blockIdx.z;
  const int co0 = blockIdx.y * 32;
  const int p = blockIdx.x * 256 + threadIdx.x;
  const int oy = p / HOUT, ox = p % HOUT;
  float acc[32];
#pragma unroll
  for (int i = 0; i < 32; ++i) acc[i] = bias[co0 + i];
  const float* inb = in + (size_t)b * CIN * HIN * HIN;
  const int iy0 = 2 * oy - 1, ix0 = 2 * ox - 1;
  for (int ci = 0; ci < CIN; ++ci) {
    float v[9];
    const float* ip = inb + (size_t)ci * HIN * HIN;
#pragma unroll
    for (int ky = 0; ky < 3; ++ky) {
      const int iy = iy0 + ky;
      const bool yok = (unsigned)iy < (unsigned)HIN;
#pragma unroll
      for (int kx = 0; kx < 3; ++kx) {
        const int ix = ix0 + kx;
        const bool ok = yok && ((unsigned)ix < (unsigned)HIN);
        v[ky * 3 + kx] = ok ? ip[iy * HIN + ix] : 0.f;
      }
    }
    const float* wp = w + ((size_t)co0 * CIN + ci) * 9;
#pragma unroll
    for (int co = 0; co < 32; ++co) {
#pragma unroll
      for (int k = 0; k < 9; ++k)
        acc[co] = fmaf(v[k], wp[(size_t)co * CIN * 9 + k], acc[co]);
    }
  }
  float* ob = out + ((size_t)b * COUT + co0) * HOUT * HOUT + p;
#pragma unroll
  for (int co = 0; co < 32; ++co) ob[(size_t)co * HOUT * HOUT] = acc[co];
}

// ---------------- transposed conv 128->256, 64x64 -> 128x128 ----------------
__global__ __launch_bounds__(256) void convt_kernel(
    const float* __restrict__ in, const float* __restrict__ w,
    const float* __restrict__ bias, float* __restrict__ out) {
  const int bz = blockIdx.z;
  const int b = bz >> 2;
  const int py = bz & 1, px = (bz >> 1) & 1;
  const int co0 = blockIdx.y * 32;
  const int p = blockIdx.x * 256 + threadIdx.x;  // 0..4095
  const int sy = p >> 6, sx = p & 63;
  const int oy = 2 * sy + py, ox = 2 * sx + px;
  const int kyA = py ? 0 : 1;
  const int kxA = px ? 0 : 1;
  const bool hasYB = py && (sy + 1 < 64);
  const bool hasXB = px && (sx + 1 < 64);
  const int kAA = kyA * 3 + kxA;
  const int kAB = kyA * 3 + 2;
  const int kBA = 6 + kxA;
  float acc[32];
#pragma unroll
  for (int i = 0; i < 32; ++i) acc[i] = bias[co0 + i];
  const float* inb = in + (size_t)b * 128 * 4096;
  for (int ci = 0; ci < 128; ++ci) {
    const float* ip = inb + ci * 4096;
    const float* wp = w + ((size_t)co0 * 128 + ci) * 9;
    const float vAA = ip[sy * 64 + sx];
    const float vAB = hasXB ? ip[sy * 64 + sx + 1] : 0.f;
    const float vBA = hasYB ? ip[(sy + 1) * 64 + sx] : 0.f;
    const float vBB = (hasYB && hasXB) ? ip[(sy + 1) * 64 + sx + 1] : 0.f;
#pragma unroll
    for (int co = 0; co < 32; ++co) {
      const float* wc = wp + (size_t)co * 128 * 9;
      acc[co] = fmaf(vAA, wc[kAA], acc[co]);
      if (px) acc[co] = fmaf(vAB, wc[kAB], acc[co]);
      if (py) acc[co] = fmaf(vBA, wc[kBA], acc[co]);
      if (py && px) acc[co] = fmaf(vBB, wc[8], acc[co]);
    }
  }
  float* ob = out + ((size_t)b * 256 + co0) * 16384;
#pragma unroll
  for (int co = 0; co < 32; ++co)
    ob[(size_t)co * 16384 + oy * 128 + ox] = acc[co];
}

// ---------------- tiled transpose: xt fp32 [b][256][16384] -> X bf16 [b][16384][256] ----------------
__global__ __launch_bounds__(256) void transpose_bf16_kernel(
    const float* __restrict__ xt, unsigned short* __restrict__ X) {
  const int b = blockIdx.y;
  const int p0 = (blockIdx.x & 255) * 64;
  const int ci0 = (blockIdx.x >> 8) * 64;
  __shared__ unsigned short T[64][66];
  const float* src = xt + (size_t)b * 256 * 16384;
  const int t = threadIdx.x;
#pragma unroll
  for (int r = 0; r < 16; ++r) {
    const int ci_l = r * 4 + (t >> 6);
    const int p_l = t & 63;
    T[ci_l][p_l] = f2bf(src[(size_t)(ci0 + ci_l) * 16384 + p0 + p_l]);
  }
  __syncthreads();
  unsigned short* dst = X + (size_t)b * 16384 * 256;
#pragma unroll
  for (int r = 0; r < 2; ++r) {
    const int p_l = r * 32 + (t >> 3);
    const int c0 = (t & 7) * 8;
    union { short8 v; unsigned short u[8]; } pk;
#pragma unroll
    for (int j = 0; j < 8; ++j) pk.u[j] = T[c0 + j][p_l];
    *(short8*)(dst + (size_t)(p0 + p_l) * 256 + ci0 + c0) = pk.v;
  }
}

// ---------------- weight repack: w3 [512][256][9] fp32 -> Wb [9][512][256] bf16 ----------------
__global__ __launch_bounds__(256) void wprep_kernel(const float* __restrict__ w3,
                                                    unsigned short* __restrict__ Wb) {
  const int i = blockIdx.x * 256 + threadIdx.x;
  if (i >= 9 * 512 * 256) return;
  const int ci = i & 255, co = (i >> 8) & 511, tap = i >> 17;
  Wb[i] = f2bf(w3[((size_t)co * 256 + ci) * 9 + tap]);
}

// ---------------- label extraction + counts from one-hot segmap ----------------
__global__ __launch_bounds__(256) void label_kernel(
    const float* __restrict__ segmap, int* __restrict__ labels,
    float* __restrict__ cnt) {
  const int b = blockIdx.y;
  const int p = blockIdx.x * 256 + threadIdx.x;  // 0..16383
  const int i = p >> 7, j = p & 127;
  const float* sp = segmap + (size_t)b * 19 * 65536 + (2 * i) * 256 + 2 * j;
  int lab = 0;
#pragma unroll
  for (int s = 0; s < 19; ++s)
    if (sp[(size_t)s * 65536] != 0.f) lab = s;
  labels[b * 16384 + p] = lab;
  atomicAdd(&cnt[b * 19 + lab], 1.0f);
}

// ---------------- conv3 as bf16 MFMA implicit GEMM + tanh + region pool -------
// Block: 256 thr = 4 waves, tile 64 pixels x 64 co, 4 strips per block.
// A (pixels x ci) staged in LDS (stride 56 ushort: 16B-aligned, 2-way banks).
// B (co x ci, K-contig) loaded straight from L2 (Wb is 2.4 MB).
// mfma_f32_16x16x32_bf16: C/D col=lane&15 (co), row=(lane>>4)*4+reg (pixel).
__global__ __launch_bounds__(256) void conv3_mfma_pool_kernel(
    const unsigned short* __restrict__ X, const unsigned short* __restrict__ Wb,
    const float* __restrict__ bias, const int* __restrict__ labels,
    float* __restrict__ sums) {
  const int b = blockIdx.z;
  const int co0 = blockIdx.y * 64;

  __shared__ unsigned short As[64][56];
  __shared__ float lsum[19 * 64];

  const int t = threadIdx.x;
  const int lane = t & 63;
  const int wave = t >> 6;
  const int wm = wave >> 1, wn = wave & 1;
  const int lg = lane >> 4, lr = lane & 15;

  for (int i = t; i < 19 * 64; i += 256) lsum[i] = 0.f;

  const int sp = t & 63;        // staged pixel within strip
  const int sci = (t >> 6) * 8; // staged ci offset within 32-chunk
  const unsigned short* Xb = X + (size_t)b * 16384 * 256;
  const float bco[2] = {bias[co0 + wn * 32 + lr], bias[co0 + wn * 32 + 16 + lr]};

  for (int s = 0; s < 4; ++s) {
    const int P0 = (blockIdx.x * 4 + s) * 64;
    const int y0 = P0 >> 7;
    const int xb0 = P0 & 127;

    f32x4 acc[2][2];
#pragma unroll
    for (int mt = 0; mt < 2; ++mt)
#pragma unroll
      for (int nt = 0; nt < 2; ++nt) {
        f32x4 z = {0.f, 0.f, 0.f, 0.f};
        acc[mt][nt] = z;
      }

#pragma unroll
    for (int tap = 0; tap < 9; ++tap) {
      const int ky = tap / 3, kx = tap % 3;
      int iy = y0 + ky - 1;
      iy = iy < 0 ? 1 : (iy > 127 ? 126 : iy);
      int ix = xb0 + sp + kx - 1;
      ix = ix < 0 ? 1 : (ix > 127 ? 126 : ix);
      const unsigned short* srow = Xb + (size_t)(iy * 128 + ix) * 256;
      const unsigned short* wtap =
          Wb + (size_t)tap * 512 * 256 + (size_t)(co0 + wn * 32) * 256;
      for (int ci0 = 0; ci0 < 256; ci0 += 32) {
        __syncthreads();
        *(short8*)&As[sp][sci] = *(const short8*)(srow + ci0 + sci);
        __syncthreads();
        short8 af[2], bf[2];
#pragma unroll
        for (int mt = 0; mt < 2; ++mt)
          af[mt] = *(const short8*)&As[wm * 32 + mt * 16 + lr][lg * 8];
#pragma unroll
        for (int nt = 0; nt < 2; ++nt)
          bf[nt] = *(const short8*)(wtap + (size_t)(nt * 16 + lr) * 256 + ci0 + lg * 8);
#pragma unroll
        for (int mt = 0; mt < 2; ++mt)
#pragma unroll
          for (int nt = 0; nt < 2; ++nt)
            acc[mt][nt] = __builtin_amdgcn_mfma_f32_16x16x32_bf16(
                af[mt], bf[nt], acc[mt][nt], 0, 0, 0);
      }
    }

    // epilogue: tanh + pool into LDS by label
    const int* labp = labels + b * 16384 + P0;
#pragma unroll
    for (int mt = 0; mt < 2; ++mt) {
#pragma unroll
      for (int r = 0; r < 4; ++r) {
        const int p_l = wm * 32 + mt * 16 + lg * 4 + r;
        const int lab = labp[p_l];
#pragma unroll
        for (int nt = 0; nt < 2; ++nt) {
          const float v = tanhf(acc[mt][nt][r] + bco[nt]);
          atomicAdd(&lsum[lab * 64 + wn * 32 + nt * 16 + lr], v);
        }
      }
    }
  }

  __syncthreads();
  for (int i = t; i < 19 * 64; i += 256) {
    const float v = lsum[i];
    if (v != 0.f) {
      const int sIdx = i >> 6, c = i & 63;
      atomicAdd(&sums[((size_t)b * 19 + sIdx) * 512 + co0 + c], v);
    }
  }
}

// ---------------- finalize: out = cnt>0 ? sums/max(cnt,1) : 0 ----------------
__global__ __launch_bounds__(256) void finalize_kernel(
    const float* __restrict__ sums, const float* __restrict__ cnt,
    float* __restrict__ out) {
  const int i = blockIdx.x * 256 + threadIdx.x;
  if (i >= B * 19 * 512) return;
  const int bs = i >> 9;
  const float c = cnt[bs];
  out[i] = c > 0.f ? sums[i] / fmaxf(c, 1.f) : 0.f;
}

// ---------------------------------------------------------------------------
extern "C" void kernel_launch(void* const* d_in, const int* in_sizes, int n_in,
                              void* d_out, int out_size, void* d_ws,
                              size_t ws_size, hipStream_t stream) {
  const float* input = (const float*)d_in[0];
  const float* segmap = (const float*)d_in[1];
  const float* w0 = (const float*)d_in[2];
  const float* b0 = (const float*)d_in[3];
  const float* w1 = (const float*)d_in[4];
  const float* b1 = (const float*)d_in[5];
  const float* w2 = (const float*)d_in[6];
  const float* b2 = (const float*)d_in[7];
  const float* wt = (const float*)d_in[8];
  const float* bt = (const float*)d_in[9];
  const float* w3 = (const float*)d_in[10];
  const float* b3 = (const float*)d_in[11];
  float* out = (float*)d_out;

  float* ws = (float*)d_ws;
  float* x0 = ws;                   // 8*32*256*256  = 16777216 f
  float* x1 = x0 + 16777216;        // 8*64*128*128  =  8388608 f
  float* x2 = x1 + 8388608;         // 8*128*64*64   =  4194304 f
  float* xt = x2 + 4194304;         // 8*256*128*128 = 33554432 f
  float* sums = xt + 33554432;      // 8*19*512      =    77824 f
  float* cnt = sums + 77824;        // 8*19          =      152 f
  int* labels = (int*)(cnt + 152);  // 8*128*128     =   131072 i
  unsigned short* Wb = (unsigned short*)(labels + 131072);  // 9*512*256 bf16
  // X (bf16, 8*16384*256 = 33554432 ushort) reuses x0's region (x0 dead after conv1)
  unsigned short* X = (unsigned short*)x0;

  hipMemsetAsync(sums, 0, (77824 + 152) * sizeof(float), stream);

  wprep_kernel<<<dim3((9 * 512 * 256 + 255) / 256), 256, 0, stream>>>(w3, Wb);
  conv0_kernel<<<dim3(256, B), 256, 0, stream>>>(input, w0, b0, x0);
  inorm_lrelu_kernel<<<dim3(B * 32), 256, 0, stream>>>(x0, 65536);
  conv_s2_kernel<32, 64, 256><<<dim3(64, 2, B), 256, 0, stream>>>(x0, w1, b1, x1);
  inorm_lrelu_kernel<<<dim3(B * 64), 256, 0, stream>>>(x1, 16384);
  conv_s2_kernel<64, 128, 128><<<dim3(16, 4, B), 256, 0, stream>>>(x1, w2, b2, x2);
  inorm_lrelu_kernel<<<dim3(B * 128), 256, 0, stream>>>(x2, 4096);
  convt_kernel<<<dim3(16, 8, B * 4), 256, 0, stream>>>(x2, wt, bt, xt);
  inorm_lrelu_kernel<<<dim3(B * 256), 256, 0, stream>>>(xt, 16384);
  transpose_bf16_kernel<<<dim3(1024, B), 256, 0, stream>>>(xt, X);
  label_kernel<<<dim3(64, B), 256, 0, stream>>>(segmap, labels, cnt);
  conv3_mfma_pool_kernel<<<dim3(64, 8, B), 256, 0, stream>>>(X, Wb, b3, labels, sums);
  finalize_kernel<<<dim3((B * 19 * 512 + 255) / 256), 256, 0, stream>>>(sums, cnt, out);
}

// Round 4
// 3511.502 us; speedup vs baseline: 3.2330x; 1.4708x over previous
//
#include <hip/hip_runtime.h>

// ---------------------------------------------------------------------------
// SPADE-style encoder. conv3 = bf16 MFMA implicit-GEMM over a reflect-padded
// input (Xpad), halo-window LDS staging (1 stage covers all 9 taps), fused
// tanh + segmap region pooling. Other layers still fp32 vector (next round).
// R4 fix: halo staging covers all 792 chunks (R3 staged only 768 -> stale LDS).
// ---------------------------------------------------------------------------

#define B 8

typedef __attribute__((ext_vector_type(8))) short short8;
typedef __attribute__((ext_vector_type(4))) float f32x4;

static __device__ __forceinline__ unsigned short f2bf(float f) {
  union { float f; unsigned u; } v;
  v.f = f;
  unsigned r = v.u + 0x7fffu + ((v.u >> 16) & 1u);
  return (unsigned short)(r >> 16);
}

static __device__ __forceinline__ float tanh_fast(float x) {
  float ax = fabsf(x);
  ax = fminf(ax, 20.f);
  const float e = __expf(-2.f * ax);
  const float t = (1.f - e) / (1.f + e);
  return __builtin_copysignf(t, x);
}

// ---------------- conv0: 3->32, reflect pad 1, 256x256 ----------------
__global__ __launch_bounds__(256) void conv0_kernel(
    const float* __restrict__ in, const float* __restrict__ w,
    const float* __restrict__ bias, float* __restrict__ out) {
  __shared__ float sw[32 * 27 + 32];
  for (int i = threadIdx.x; i < 32 * 27; i += 256) sw[i] = w[i];
  if (threadIdx.x < 32) sw[32 * 27 + threadIdx.x] = bias[threadIdx.x];
  __syncthreads();
  const int b = blockIdx.y;
  const int p = blockIdx.x * 256 + threadIdx.x;
  const int y = p >> 8, x = p & 255;
  const float* inb = in + (size_t)b * 3 * 65536;
  float v[27];
#pragma unroll
  for (int c = 0; c < 3; ++c) {
#pragma unroll
    for (int ky = 0; ky < 3; ++ky) {
      int iy = y + ky - 1;
      iy = iy < 0 ? -iy : (iy > 255 ? 510 - iy : iy);
#pragma unroll
      for (int kx = 0; kx < 3; ++kx) {
        int ix = x + kx - 1;
        ix = ix < 0 ? -ix : (ix > 255 ? 510 - ix : ix);
        v[c * 9 + ky * 3 + kx] = inb[c * 65536 + iy * 256 + ix];
      }
    }
  }
  float* ob = out + (size_t)b * 32 * 65536 + p;
#pragma unroll
  for (int co = 0; co < 32; ++co) {
    float a = sw[32 * 27 + co];
#pragma unroll
    for (int k = 0; k < 27; ++k) a = fmaf(v[k], sw[co * 27 + k], a);
    ob[(size_t)co * 65536] = a;
  }
}

// ---------------- fused instance-norm + leaky relu (in place) ----------------
__global__ __launch_bounds__(256) void inorm_lrelu_kernel(float* __restrict__ x,
                                                          int HW) {
  const size_t base = (size_t)blockIdx.x * HW;
  float4* p = (float4*)(x + base);
  const int n4 = HW >> 2;
  float s = 0.f, q = 0.f;
  for (int i = threadIdx.x; i < n4; i += 256) {
    float4 v = p[i];
    s += (v.x + v.y) + (v.z + v.w);
    q += (v.x * v.x + v.y * v.y) + (v.z * v.z + v.w * v.w);
  }
  __shared__ float rs[256], rq[256];
  rs[threadIdx.x] = s;
  rq[threadIdx.x] = q;
  __syncthreads();
  for (int st = 128; st > 0; st >>= 1) {
    if (threadIdx.x < st) {
      rs[threadIdx.x] += rs[threadIdx.x + st];
      rq[threadIdx.x] += rq[threadIdx.x + st];
    }
    __syncthreads();
  }
  const float m = rs[0] / (float)HW;
  float var = rq[0] / (float)HW - m * m;
  var = var < 0.f ? 0.f : var;
  const float r = rsqrtf(var + 1e-5f);
  for (int i = threadIdx.x; i < n4; i += 256) {
    float4 v = p[i];
    v.x = (v.x - m) * r; v.x = v.x >= 0.f ? v.x : 0.2f * v.x;
    v.y = (v.y - m) * r; v.y = v.y >= 0.f ? v.y : 0.2f * v.y;
    v.z = (v.z - m) * r; v.z = v.z >= 0.f ? v.z : 0.2f * v.z;
    v.w = (v.w - m) * r; v.w = v.w >= 0.f ? v.w : 0.2f * v.w;
    p[i] = v;
  }
}

// ---------------- 3x3 stride-2 zero-pad-1 conv, 32 co per block ----------------
template <int CIN, int COUT, int HIN>
__global__ __launch_bounds__(256) void conv_s2_kernel(
    const float* __restrict__ in, const float* __restrict__ w,
    const float* __restrict__ bias, float* __restrict__ out) {
  constexpr int HOUT = HIN / 2;
  const int b = blockIdx.z;
  const int co0 = blockIdx.y * 32;
  const int p = blockIdx.x * 256 + threadIdx.x;
  const int oy = p / HOUT, ox = p % HOUT;
  float acc[32];
#pragma unroll
  for (int i = 0; i < 32; ++i) acc[i] = bias[co0 + i];
  const float* inb = in + (size_t)b * CIN * HIN * HIN;
  const int iy0 = 2 * oy - 1, ix0 = 2 * ox - 1;
  for (int ci = 0; ci < CIN; ++ci) {
    float v[9];
    const float* ip = inb + (size_t)ci * HIN * HIN;
#pragma unroll
    for (int ky = 0; ky < 3; ++ky) {
      const int iy = iy0 + ky;
      const bool yok = (unsigned)iy < (unsigned)HIN;
#pragma unroll
      for (int kx = 0; kx < 3; ++kx) {
        const int ix = ix0 + kx;
        const bool ok = yok && ((unsigned)ix < (unsigned)HIN);
        v[ky * 3 + kx] = ok ? ip[iy * HIN + ix] : 0.f;
      }
    }
    const float* wp = w + ((size_t)co0 * CIN + ci) * 9;
#pragma unroll
    for (int co = 0; co < 32; ++co) {
#pragma unroll
      for (int k = 0; k < 9; ++k)
        acc[co] = fmaf(v[k], wp[(size_t)co * CIN * 9 + k], acc[co]);
    }
  }
  float* ob = out + ((size_t)b * COUT + co0) * HOUT * HOUT + p;
#pragma unroll
  for (int co = 0; co < 32; ++co) ob[(size_t)co * HOUT * HOUT] = acc[co];
}

// ---------------- transposed conv 128->256, 64x64 -> 128x128 ----------------
__global__ __launch_bounds__(256) void convt_kernel(
    const float* __restrict__ in, const float* __restrict__ w,
    const float* __restrict__ bias, float* __restrict__ out) {
  const int bz = blockIdx.z;
  const int b = bz >> 2;
  const int py = bz & 1, px = (bz >> 1) & 1;
  const int co0 = blockIdx.y * 32;
  const int p = blockIdx.x * 256 + threadIdx.x;  // 0..4095
  const int sy = p >> 6, sx = p & 63;
  const int oy = 2 * sy + py, ox = 2 * sx + px;
  const int kyA = py ? 0 : 1;
  const int kxA = px ? 0 : 1;
  const bool hasYB = py && (sy + 1 < 64);
  const bool hasXB = px && (sx + 1 < 64);
  const int kAA = kyA * 3 + kxA;
  const int kAB = kyA * 3 + 2;
  const int kBA = 6 + kxA;
  float acc[32];
#pragma unroll
  for (int i = 0; i < 32; ++i) acc[i] = bias[co0 + i];
  const float* inb = in + (size_t)b * 128 * 4096;
  for (int ci = 0; ci < 128; ++ci) {
    const float* ip = inb + ci * 4096;
    const float* wp = w + ((size_t)co0 * 128 + ci) * 9;
    const float vAA = ip[sy * 64 + sx];
    const float vAB = hasXB ? ip[sy * 64 + sx + 1] : 0.f;
    const float vBA = hasYB ? ip[(sy + 1) * 64 + sx] : 0.f;
    const float vBB = (hasYB && hasXB) ? ip[(sy + 1) * 64 + sx + 1] : 0.f;
#pragma unroll
    for (int co = 0; co < 32; ++co) {
      const float* wc = wp + (size_t)co * 128 * 9;
      acc[co] = fmaf(vAA, wc[kAA], acc[co]);
      if (px) acc[co] = fmaf(vAB, wc[kAB], acc[co]);
      if (py) acc[co] = fmaf(vBA, wc[kBA], acc[co]);
      if (py && px) acc[co] = fmaf(vBB, wc[8], acc[co]);
    }
  }
  float* ob = out + ((size_t)b * 256 + co0) * 16384;
#pragma unroll
  for (int co = 0; co < 32; ++co)
    ob[(size_t)co * 16384 + oy * 128 + ox] = acc[co];
}

// -------- transpose + pad-shift: xt fp32 [b][256][16384] -> Xpad bf16
// -------- [b][130][130][256], writing interior rows/cols 1..128 ----------
__global__ __launch_bounds__(256) void transpose_bf16_kernel(
    const float* __restrict__ xt, unsigned short* __restrict__ Xpad) {
  const int b = blockIdx.y;
  const int p0 = (blockIdx.x & 255) * 64;
  const int ci0 = (blockIdx.x >> 8) * 64;
  __shared__ unsigned short T[64][66];
  const float* src = xt + (size_t)b * 256 * 16384;
  const int t = threadIdx.x;
#pragma unroll
  for (int r = 0; r < 16; ++r) {
    const int ci_l = r * 4 + (t >> 6);
    const int p_l = t & 63;
    T[ci_l][p_l] = f2bf(src[(size_t)(ci0 + ci_l) * 16384 + p0 + p_l]);
  }
  __syncthreads();
  unsigned short* dst = Xpad + (size_t)b * 130 * 130 * 256;
#pragma unroll
  for (int r = 0; r < 2; ++r) {
    const int p_l = r * 32 + (t >> 3);
    const int c0 = (t & 7) * 8;
    union { short8 v; unsigned short u[8]; } pk;
#pragma unroll
    for (int j = 0; j < 8; ++j) pk.u[j] = T[c0 + j][p_l];
    const int p = p0 + p_l;
    const int yy = p >> 7, xx = p & 127;
    *(short8*)(dst + ((size_t)(yy + 1) * 130 + (xx + 1)) * 256 + ci0 + c0) = pk.v;
  }
}

// ---------------- reflect borders of Xpad: rows then cols ----------------
__global__ __launch_bounds__(256) void pad_rows_kernel(unsigned short* __restrict__ Xp) {
  const int b = blockIdx.x >> 1, side = blockIdx.x & 1;
  unsigned short* Xb = Xp + (size_t)b * 130 * 130 * 256;
  const int dr = side ? 129 : 0, sr = side ? 127 : 2;
  for (int i = threadIdx.x; i < 4096; i += 256) {
    const int c = 1 + (i >> 5), o = (i & 31) * 8;
    *(short8*)(Xb + ((size_t)dr * 130 + c) * 256 + o) =
        *(const short8*)(Xb + ((size_t)sr * 130 + c) * 256 + o);
  }
}
__global__ __launch_bounds__(256) void pad_cols_kernel(unsigned short* __restrict__ Xp) {
  const int b = blockIdx.x >> 1, side = blockIdx.x & 1;
  unsigned short* Xb = Xp + (size_t)b * 130 * 130 * 256;
  const int dc = side ? 129 : 0, sc = side ? 127 : 2;
  for (int i = threadIdx.x; i < 130 * 32; i += 256) {
    const int r = i >> 5, o = (i & 31) * 8;
    *(short8*)(Xb + ((size_t)r * 130 + dc) * 256 + o) =
        *(const short8*)(Xb + ((size_t)r * 130 + sc) * 256 + o);
  }
}

// ---------------- weight repack: w3 [512][256][9] fp32 -> Wb [9][512][256] bf16 ----------------
__global__ __launch_bounds__(256) void wprep_kernel(const float* __restrict__ w3,
                                                    unsigned short* __restrict__ Wb) {
  const int i = blockIdx.x * 256 + threadIdx.x;
  if (i >= 9 * 512 * 256) return;
  const int ci = i & 255, co = (i >> 8) & 511, tap = i >> 17;
  Wb[i] = f2bf(w3[((size_t)co * 256 + ci) * 9 + tap]);
}

// ---------------- label extraction + counts from one-hot segmap ----------------
__global__ __launch_bounds__(256) void label_kernel(
    const float* __restrict__ segmap, int* __restrict__ labels,
    float* __restrict__ cnt) {
  const int b = blockIdx.y;
  const int p = blockIdx.x * 256 + threadIdx.x;  // 0..16383
  const int i = p >> 7, j = p & 127;
  const float* sp = segmap + (size_t)b * 19 * 65536 + (2 * i) * 256 + 2 * j;
  int lab = 0;
#pragma unroll
  for (int s = 0; s < 19; ++s)
    if (sp[(size_t)s * 65536] != 0.f) lab = s;
  labels[b * 16384 + p] = lab;
  atomicAdd(&cnt[b * 19 + lab], 1.0f);
}

// ---------------- conv3: bf16 MFMA implicit GEMM + tanh + region pool --------
// Block = 1 strip (64 px of one row) x 256 co (4 waves, wave tile 64x64).
// Per ci-chunk(32): stage 3x66x32 halo window once -> serves all 9 taps.
// One barrier per chunk, double-buffered LDS, stride-40 rows (2-way banks).
// 792 16B-chunks per stage; 256 threads x 4 slots (slot 3 active for t<24).
__global__ __launch_bounds__(256, 3) void conv3_mfma_pool_kernel(
    const unsigned short* __restrict__ Xpad, const unsigned short* __restrict__ Wb,
    const float* __restrict__ bias, const int* __restrict__ labels,
    float* __restrict__ sums) {
  // XCD-bijective swizzle: 4096 blocks = 8 XCDs x 512 (one batch per XCD)
  const int raw = blockIdx.x;
  const int swz = (raw & 7) * 512 + (raw >> 3);
  const int b = swz >> 9;
  const int rem = swz & 511;
  const int strip = rem >> 1;
  const int coh = rem & 1;
  const int y = strip >> 1;
  const int x0 = (strip & 1) * 64;

  constexpr int RS = 40;            // LDS row stride in ushort (80B)
  constexpr int BUFN = 3 * 66 * RS; // 7920 ushort per buffer
  __shared__ unsigned short Asw[2 * BUFN];
  __shared__ float lsum[19 * 256];

  const int t = threadIdx.x;
  const int lane = t & 63;
  const int wn = t >> 6;
  const int lg = lane >> 4, lr = lane & 15;
  const int co_w = coh * 256 + wn * 64;  // global co base for this wave

  for (int i = t; i < 19 * 256; i += 256) lsum[i] = 0.f;

  const unsigned short* Xb = Xpad + (size_t)b * 130 * 130 * 256;

  // stage-chunk decomposition: 792 16B-chunks = (r<3, c<66, h<4)
  int dof0, dof1, dof2, dof3;
  const unsigned short *sp0, *sp1, *sp2, *sp3;
  bool sv3;
  {
    const int i0 = t, i1 = t + 256, i2 = t + 512, i3 = t + 768;
    const int r0 = i0 / 264, c0 = (i0 % 264) >> 2, h0 = i0 & 3;
    const int r1 = i1 / 264, c1 = (i1 % 264) >> 2, h1 = i1 & 3;
    const int r2 = i2 / 264, c2 = (i2 % 264) >> 2, h2 = i2 & 3;
    sv3 = i3 < 792;
    const int i3c = sv3 ? i3 : 768;
    const int r3 = i3c / 264, c3 = (i3c % 264) >> 2, h3 = i3c & 3;
    dof0 = (r0 * 66 + c0) * RS + h0 * 8;
    dof1 = (r1 * 66 + c1) * RS + h1 * 8;
    dof2 = (r2 * 66 + c2) * RS + h2 * 8;
    dof3 = (r3 * 66 + c3) * RS + h3 * 8;
    sp0 = Xb + ((size_t)(y + r0) * 130 + x0 + c0) * 256 + h0 * 8;
    sp1 = Xb + ((size_t)(y + r1) * 130 + x0 + c1) * 256 + h1 * 8;
    sp2 = Xb + ((size_t)(y + r2) * 130 + x0 + c2) * 256 + h2 * 8;
    sp3 = Xb + ((size_t)(y + r3) * 130 + x0 + c3) * 256 + h3 * 8;
  }

  f32x4 acc[4][4];
#pragma unroll
  for (int mt = 0; mt < 4; ++mt)
#pragma unroll
    for (int nt = 0; nt < 4; ++nt) {
      f32x4 z = {0.f, 0.f, 0.f, 0.f};
      acc[mt][nt] = z;
    }

  // prologue: stage chunk 0 into buffer 0
  {
    const short8 a = *(const short8*)sp0;
    const short8 bq = *(const short8*)sp1;
    const short8 cq = *(const short8*)sp2;
    short8 dq;
    if (sv3) dq = *(const short8*)sp3;
    *(short8*)(Asw + dof0) = a;
    *(short8*)(Asw + dof1) = bq;
    *(short8*)(Asw + dof2) = cq;
    if (sv3) *(short8*)(Asw + dof3) = dq;
  }
  __syncthreads();

  for (int c8 = 0; c8 < 8; ++c8) {
    short8 n0, n1, n2, n3;
    if (c8 < 7) {
      const int cn = (c8 + 1) * 32;
      n0 = *(const short8*)(sp0 + cn);
      n1 = *(const short8*)(sp1 + cn);
      n2 = *(const short8*)(sp2 + cn);
      if (sv3) n3 = *(const short8*)(sp3 + cn);
    }
    const unsigned short* Ab = Asw + (c8 & 1) * BUFN;
#pragma unroll
    for (int ky = 0; ky < 3; ++ky) {
#pragma unroll
      for (int kx = 0; kx < 3; ++kx) {
        short8 af[4];
#pragma unroll
        for (int mt = 0; mt < 4; ++mt) {
          const int px = mt * 16 + lr + kx;
          af[mt] = *(const short8*)(Ab + (ky * 66 + px) * RS + lg * 8);
        }
        const unsigned short* wt_ =
            Wb + (size_t)((ky * 3 + kx) * 512 + co_w + lr) * 256 + c8 * 32 + lg * 8;
#pragma unroll
        for (int nt = 0; nt < 4; ++nt) {
          const short8 bf = *(const short8*)(wt_ + nt * 16 * 256);
#pragma unroll
          for (int mt = 0; mt < 4; ++mt)
            acc[mt][nt] = __builtin_amdgcn_mfma_f32_16x16x32_bf16(
                af[mt], bf, acc[mt][nt], 0, 0, 0);
        }
      }
    }
    if (c8 < 7) {
      unsigned short* Db = Asw + ((c8 + 1) & 1) * BUFN;
      *(short8*)(Db + dof0) = n0;
      *(short8*)(Db + dof1) = n1;
      *(short8*)(Db + dof2) = n2;
      if (sv3) *(short8*)(Db + dof3) = n3;
    }
    __syncthreads();
  }

  // epilogue: bias + tanh + pool by label into LDS
  const int* labp = labels + b * 16384 + y * 128 + x0;
  float bco[4];
#pragma unroll
  for (int nt = 0; nt < 4; ++nt) bco[nt] = bias[co_w + nt * 16 + lr];
#pragma unroll
  for (int mt = 0; mt < 4; ++mt) {
#pragma unroll
    for (int r = 0; r < 4; ++r) {
      const int lab = labp[mt * 16 + lg * 4 + r];
#pragma unroll
      for (int nt = 0; nt < 4; ++nt) {
        const float v = tanh_fast(acc[mt][nt][r] + bco[nt]);
        atomicAdd(&lsum[lab * 256 + wn * 64 + nt * 16 + lr], v);
      }
    }
  }
  __syncthreads();
  for (int i = t; i < 19 * 256; i += 256) {
    const float v = lsum[i];
    if (v != 0.f) {
      const int sI = i >> 8, c = i & 255;
      atomicAdd(&sums[((size_t)b * 19 + sI) * 512 + coh * 256 + c], v);
    }
  }
}

// ---------------- finalize: out = cnt>0 ? sums/max(cnt,1) : 0 ----------------
__global__ __launch_bounds__(256) void finalize_kernel(
    const float* __restrict__ sums, const float* __restrict__ cnt,
    float* __restrict__ out) {
  const int i = blockIdx.x * 256 + threadIdx.x;
  if (i >= B * 19 * 512) return;
  const int bs = i >> 9;
  const float c = cnt[bs];
  out[i] = c > 0.f ? sums[i] / fmaxf(c, 1.f) : 0.f;
}

// ---------------------------------------------------------------------------
extern "C" void kernel_launch(void* const* d_in, const int* in_sizes, int n_in,
                              void* d_out, int out_size, void* d_ws,
                              size_t ws_size, hipStream_t stream) {
  const float* input = (const float*)d_in[0];
  const float* segmap = (const float*)d_in[1];
  const float* w0 = (const float*)d_in[2];
  const float* b0 = (const float*)d_in[3];
  const float* w1 = (const float*)d_in[4];
  const float* b1 = (const float*)d_in[5];
  const float* w2 = (const float*)d_in[6];
  const float* b2 = (const float*)d_in[7];
  const float* wt = (const float*)d_in[8];
  const float* bt = (const float*)d_in[9];
  const float* w3 = (const float*)d_in[10];
  const float* b3 = (const float*)d_in[11];
  float* out = (float*)d_out;

  float* ws = (float*)d_ws;
  float* x0 = ws;                   // 16,777,216 f   [conv0 out; dead after conv1]
  float* x1 = x0 + 16777216;        //  8,388,608 f   [dead after conv2]
  float* x2 = x1 + 8388608;         //  4,194,304 f
  float* xt = x2 + 4194304;         // 33,554,432 f
  float* sums = xt + 33554432;      //     77,824 f
  float* cnt = sums + 77824;        //        152 f
  int* labels = (int*)(cnt + 152);  //    131,072 i
  unsigned short* Wb = (unsigned short*)(labels + 131072);  // 9*512*256 bf16
  // Xpad bf16 [8][130][130][256] = 34,611,200 ushort = 69.2MB; reuses the
  // x0+x1 region (both dead by transpose time; 100.6MB available).
  unsigned short* Xpad = (unsigned short*)ws;

  hipMemsetAsync(sums, 0, (77824 + 152) * sizeof(float), stream);

  wprep_kernel<<<dim3((9 * 512 * 256 + 255) / 256), 256, 0, stream>>>(w3, Wb);
  conv0_kernel<<<dim3(256, B), 256, 0, stream>>>(input, w0, b0, x0);
  inorm_lrelu_kernel<<<dim3(B * 32), 256, 0, stream>>>(x0, 65536);
  conv_s2_kernel<32, 64, 256><<<dim3(64, 2, B), 256, 0, stream>>>(x0, w1, b1, x1);
  inorm_lrelu_kernel<<<dim3(B * 64), 256, 0, stream>>>(x1, 16384);
  conv_s2_kernel<64, 128, 128><<<dim3(16, 4, B), 256, 0, stream>>>(x1, w2, b2, x2);
  inorm_lrelu_kernel<<<dim3(B * 128), 256, 0, stream>>>(x2, 4096);
  convt_kernel<<<dim3(16, 8, B * 4), 256, 0, stream>>>(x2, wt, bt, xt);
  inorm_lrelu_kernel<<<dim3(B * 256), 256, 0, stream>>>(xt, 16384);
  transpose_bf16_kernel<<<dim3(1024, B), 256, 0, stream>>>(xt, Xpad);
  pad_rows_kernel<<<dim3(2 * B), 256, 0, stream>>>(Xpad);
  pad_cols_kernel<<<dim3(2 * B), 256, 0, stream>>>(Xpad);
  label_kernel<<<dim3(64, B), 256, 0, stream>>>(segmap, labels, cnt);
  conv3_mfma_pool_kernel<<<dim3(4096), 256, 0, stream>>>(Xpad, Wb, b3, labels, sums);
  finalize_kernel<<<dim3((B * 19 * 512 + 255) / 256), 256, 0, stream>>>(sums, cnt, out);
}

// Round 5
// 1524.111 us; speedup vs baseline: 7.4488x; 2.3040x over previous
//
#include <hip/hip_runtime.h>

// ---------------------------------------------------------------------------
// SPADE-style encoder.
// conv3: bf16 MFMA implicit-GEMM (halo LDS staging) + tanh + region pool.
// convT: NEW bf16 MFMA per-parity-class GEMM (R5), writes pixel-major Y;
//        instance-norm done as stats+apply on Y, applied result written
//        straight into Xpad interior (transpose kernel deleted).
// conv0/conv1/conv2 + their instance-norms still fp32 vector.
// ---------------------------------------------------------------------------

#define B 8

typedef __attribute__((ext_vector_type(8))) short short8;
typedef __attribute__((ext_vector_type(4))) float f32x4;

static __device__ __forceinline__ unsigned short f2bf(float f) {
  union { float f; unsigned u; } v;
  v.f = f;
  unsigned r = v.u + 0x7fffu + ((v.u >> 16) & 1u);
  return (unsigned short)(r >> 16);
}
static __device__ __forceinline__ float bf2f(unsigned short h) {
  union { unsigned u; float f; } v;
  v.u = (unsigned)h << 16;
  return v.f;
}
static __device__ __forceinline__ float tanh_fast(float x) {
  float ax = fabsf(x);
  ax = fminf(ax, 20.f);
  const float e = __expf(-2.f * ax);
  const float t = (1.f - e) / (1.f + e);
  return __builtin_copysignf(t, x);
}

// ---------------- conv0: 3->32, reflect pad 1, 256x256 ----------------
__global__ __launch_bounds__(256) void conv0_kernel(
    const float* __restrict__ in, const float* __restrict__ w,
    const float* __restrict__ bias, float* __restrict__ out) {
  __shared__ float sw[32 * 27 + 32];
  for (int i = threadIdx.x; i < 32 * 27; i += 256) sw[i] = w[i];
  if (threadIdx.x < 32) sw[32 * 27 + threadIdx.x] = bias[threadIdx.x];
  __syncthreads();
  const int b = blockIdx.y;
  const int p = blockIdx.x * 256 + threadIdx.x;
  const int y = p >> 8, x = p & 255;
  const float* inb = in + (size_t)b * 3 * 65536;
  float v[27];
#pragma unroll
  for (int c = 0; c < 3; ++c) {
#pragma unroll
    for (int ky = 0; ky < 3; ++ky) {
      int iy = y + ky - 1;
      iy = iy < 0 ? -iy : (iy > 255 ? 510 - iy : iy);
#pragma unroll
      for (int kx = 0; kx < 3; ++kx) {
        int ix = x + kx - 1;
        ix = ix < 0 ? -ix : (ix > 255 ? 510 - ix : ix);
        v[c * 9 + ky * 3 + kx] = inb[c * 65536 + iy * 256 + ix];
      }
    }
  }
  float* ob = out + (size_t)b * 32 * 65536 + p;
#pragma unroll
  for (int co = 0; co < 32; ++co) {
    float a = sw[32 * 27 + co];
#pragma unroll
    for (int k = 0; k < 27; ++k) a = fmaf(v[k], sw[co * 27 + k], a);
    ob[(size_t)co * 65536] = a;
  }
}

// ---------------- fused instance-norm + leaky relu (in place, fp32) ----------
__global__ __launch_bounds__(256) void inorm_lrelu_kernel(float* __restrict__ x,
                                                          int HW) {
  const size_t base = (size_t)blockIdx.x * HW;
  float4* p = (float4*)(x + base);
  const int n4 = HW >> 2;
  float s = 0.f, q = 0.f;
  for (int i = threadIdx.x; i < n4; i += 256) {
    float4 v = p[i];
    s += (v.x + v.y) + (v.z + v.w);
    q += (v.x * v.x + v.y * v.y) + (v.z * v.z + v.w * v.w);
  }
  __shared__ float rs[256], rq[256];
  rs[threadIdx.x] = s;
  rq[threadIdx.x] = q;
  __syncthreads();
  for (int st = 128; st > 0; st >>= 1) {
    if (threadIdx.x < st) {
      rs[threadIdx.x] += rs[threadIdx.x + st];
      rq[threadIdx.x] += rq[threadIdx.x + st];
    }
    __syncthreads();
  }
  const float m = rs[0] / (float)HW;
  float var = rq[0] / (float)HW - m * m;
  var = var < 0.f ? 0.f : var;
  const float r = rsqrtf(var + 1e-5f);
  for (int i = threadIdx.x; i < n4; i += 256) {
    float4 v = p[i];
    v.x = (v.x - m) * r; v.x = v.x >= 0.f ? v.x : 0.2f * v.x;
    v.y = (v.y - m) * r; v.y = v.y >= 0.f ? v.y : 0.2f * v.y;
    v.z = (v.z - m) * r; v.z = v.z >= 0.f ? v.z : 0.2f * v.z;
    v.w = (v.w - m) * r; v.w = v.w >= 0.f ? v.w : 0.2f * v.w;
    p[i] = v;
  }
}

// ---------------- 3x3 stride-2 zero-pad-1 conv, 32 co per block ----------------
template <int CIN, int COUT, int HIN>
__global__ __launch_bounds__(256) void conv_s2_kernel(
    const float* __restrict__ in, const float* __restrict__ w,
    const float* __restrict__ bias, float* __restrict__ out) {
  constexpr int HOUT = HIN / 2;
  const int b = blockIdx.z;
  const int co0 = blockIdx.y * 32;
  const int p = blockIdx.x * 256 + threadIdx.x;
  const int oy = p / HOUT, ox = p % HOUT;
  float acc[32];
#pragma unroll
  for (int i = 0; i < 32; ++i) acc[i] = bias[co0 + i];
  const float* inb = in + (size_t)b * CIN * HIN * HIN;
  const int iy0 = 2 * oy - 1, ix0 = 2 * ox - 1;
  for (int ci = 0; ci < CIN; ++ci) {
    float v[9];
    const float* ip = inb + (size_t)ci * HIN * HIN;
#pragma unroll
    for (int ky = 0; ky < 3; ++ky) {
      const int iy = iy0 + ky;
      const bool yok = (unsigned)iy < (unsigned)HIN;
#pragma unroll
      for (int kx = 0; kx < 3; ++kx) {
        const int ix = ix0 + kx;
        const bool ok = yok && ((unsigned)ix < (unsigned)HIN);
        v[ky * 3 + kx] = ok ? ip[iy * HIN + ix] : 0.f;
      }
    }
    const float* wp = w + ((size_t)co0 * CIN + ci) * 9;
#pragma unroll
    for (int co = 0; co < 32; ++co) {
#pragma unroll
      for (int k = 0; k < 9; ++k)
        acc[co] = fmaf(v[k], wp[(size_t)co * CIN * 9 + k], acc[co]);
    }
  }
  float* ob = out + ((size_t)b * COUT + co0) * HOUT * HOUT + p;
#pragma unroll
  for (int co = 0; co < 32; ++co) ob[(size_t)co * HOUT * HOUT] = acc[co];
}

// -------- transpose x2: fp32 [b][128][4096] -> X2p bf16 [b][65][65][128] ----
__global__ __launch_bounds__(256) void transpose_x2_kernel(
    const float* __restrict__ x2, unsigned short* __restrict__ X2p) {
  const int b = blockIdx.y;
  const int p0 = (blockIdx.x & 63) * 64;
  const int ci0 = (blockIdx.x >> 6) * 64;
  __shared__ unsigned short T[64][66];
  const float* src = x2 + (size_t)b * 128 * 4096;
  const int t = threadIdx.x;
#pragma unroll
  for (int r = 0; r < 16; ++r) {
    const int ci_l = r * 4 + (t >> 6);
    const int p_l = t & 63;
    T[ci_l][p_l] = f2bf(src[(size_t)(ci0 + ci_l) * 4096 + p0 + p_l]);
  }
  __syncthreads();
  unsigned short* dst = X2p + (size_t)b * 65 * 65 * 128;
#pragma unroll
  for (int r = 0; r < 2; ++r) {
    const int p_l = r * 32 + (t >> 3);
    const int c0 = (t & 7) * 8;
    union { short8 v; unsigned short u[8]; } pk;
#pragma unroll
    for (int j = 0; j < 8; ++j) pk.u[j] = T[c0 + j][p_l];
    const int p = p0 + p_l;
    const int yy = p >> 6, xx = p & 63;
    *(short8*)(dst + ((size_t)yy * 65 + xx) * 128 + ci0 + c0) = pk.v;
  }
}

// ---------------- zero pad row 64 / col 64 of X2p ----------------
__global__ __launch_bounds__(256) void zpad_x2_kernel(unsigned short* __restrict__ X2p) {
  const int b = blockIdx.x;
  unsigned short* Xb = X2p + (size_t)b * 65 * 65 * 128;
  for (int i = threadIdx.x; i < 129 * 128; i += 256) {
    const int j = i >> 7, ci = i & 127;
    size_t off;
    if (j < 65) off = ((size_t)64 * 65 + j) * 128 + ci;      // bottom row
    else off = ((size_t)(j - 65) * 65 + 64) * 128 + ci;      // right col
    Xb[off] = 0;
  }
}

// -------- weight repack: wt [256][128][3][3] fp32 -> Wtb [9][256][128] bf16 --
__global__ __launch_bounds__(256) void wtprep_kernel(const float* __restrict__ wt,
                                                     unsigned short* __restrict__ Wtb) {
  const int i = blockIdx.x * 256 + threadIdx.x;
  if (i >= 9 * 256 * 128) return;
  const int ci = i & 127, co = (i >> 7) & 255, tap = i >> 15;
  Wtb[i] = f2bf(wt[((size_t)co * 128 + ci) * 9 + tap]);
}

// ---------------- convT as bf16 MFMA per-parity-class GEMM ----------------
// Block = (b, class(py,px), sy): 64 strip pixels x 256 co; 4 waves x (64x64).
// K = 128 ci x ntaps{1,2,2,4}; per 32-ci chunk stage 2x65 halo once.
// Zero-padded X2p row/col 64 -> no boundary branches.
__global__ __launch_bounds__(256, 3) void convt_mfma_kernel(
    const unsigned short* __restrict__ X2p, const unsigned short* __restrict__ Wtb,
    const float* __restrict__ bt, unsigned short* __restrict__ Y) {
  // XCD swizzle: 2048 = 8 x 256 -> each XCD owns one batch (X2p slice L2-fits)
  const int raw = blockIdx.x;
  const int swz = (raw & 7) * 256 + (raw >> 3);
  const int b = swz >> 8;
  const int rem = swz & 255;
  const int cls = rem >> 6;
  const int sy = rem & 63;
  const int py = cls & 1, px = cls >> 1;

  const int kyA = py ? 0 : 1, kxA = px ? 0 : 1;
  int tk[4], tdy[4], tdx[4];
  int ntaps = 0;
  tk[ntaps] = kyA * 3 + kxA; tdy[ntaps] = 0; tdx[ntaps] = 0; ++ntaps;
  if (px) { tk[ntaps] = kyA * 3 + 2; tdy[ntaps] = 0; tdx[ntaps] = 1; ++ntaps; }
  if (py) { tk[ntaps] = 6 + kxA; tdy[ntaps] = 1; tdx[ntaps] = 0; ++ntaps; }
  if (py && px) { tk[ntaps] = 8; tdy[ntaps] = 1; tdx[ntaps] = 1; ++ntaps; }

  constexpr int CS = 36;             // LDS col stride (72B -> ~2-way banks)
  constexpr int BUFN = 2 * 65 * CS;  // 4680 ushort
  __shared__ unsigned short As2[2 * BUFN];

  const int t = threadIdx.x;
  const int lane = t & 63;
  const int wn = t >> 6;
  const int lg = lane >> 4, lr = lane & 15;
  const int co_w = wn * 64;

  const unsigned short* Xb = X2p + (size_t)b * 65 * 65 * 128;

  // staging: 520 16B-chunks = r(2) x c(65) x h(4); slots t, t+256, t+512
  int dof0, dof1, dof2;
  const unsigned short *sp0, *sp1, *sp2;
  bool sv2;
  {
    const int i0 = t, i1 = t + 256, i2 = t + 512;
    const int r0 = i0 / 260, c0_ = (i0 % 260) >> 2, h0 = i0 & 3;
    const int r1 = i1 / 260, c1_ = (i1 % 260) >> 2, h1 = i1 & 3;
    sv2 = i2 < 520;
    const int i2c = sv2 ? i2 : 512;
    const int r2 = i2c / 260, c2_ = (i2c % 260) >> 2, h2 = i2c & 3;
    dof0 = (r0 * 65 + c0_) * CS + h0 * 8;
    dof1 = (r1 * 65 + c1_) * CS + h1 * 8;
    dof2 = (r2 * 65 + c2_) * CS + h2 * 8;
    sp0 = Xb + ((size_t)(sy + r0) * 65 + c0_) * 128 + h0 * 8;
    sp1 = Xb + ((size_t)(sy + r1) * 65 + c1_) * 128 + h1 * 8;
    sp2 = Xb + ((size_t)(sy + r2) * 65 + c2_) * 128 + h2 * 8;
  }

  f32x4 acc[4][4];
#pragma unroll
  for (int mt = 0; mt < 4; ++mt)
#pragma unroll
    for (int nt = 0; nt < 4; ++nt) {
      f32x4 z = {0.f, 0.f, 0.f, 0.f};
      acc[mt][nt] = z;
    }

  // prologue: stage ci-chunk 0 into buffer 0
  {
    const short8 a = *(const short8*)sp0;
    const short8 bq = *(const short8*)sp1;
    short8 cq;
    if (sv2) cq = *(const short8*)sp2;
    *(short8*)(As2 + dof0) = a;
    *(short8*)(As2 + dof1) = bq;
    if (sv2) *(short8*)(As2 + dof2) = cq;
  }
  __syncthreads();

  for (int c8 = 0; c8 < 4; ++c8) {
    short8 n0, n1, n2;
    if (c8 < 3) {
      const int cn = (c8 + 1) * 32;
      n0 = *(const short8*)(sp0 + cn);
      n1 = *(const short8*)(sp1 + cn);
      if (sv2) n2 = *(const short8*)(sp2 + cn);
    }
    const unsigned short* Ab = As2 + (c8 & 1) * BUFN;
    for (int tp = 0; tp < ntaps; ++tp) {
      const int dy = tdy[tp], dx = tdx[tp];
      short8 af[4];
#pragma unroll
      for (int mt = 0; mt < 4; ++mt)
        af[mt] = *(const short8*)(Ab + (dy * 65 + mt * 16 + lr + dx) * CS + lg * 8);
      const unsigned short* wt_ =
          Wtb + ((size_t)(tk[tp] * 256 + co_w + lr) * 128) + c8 * 32 + lg * 8;
#pragma unroll
      for (int nt = 0; nt < 4; ++nt) {
        const short8 bf = *(const short8*)(wt_ + (size_t)nt * 16 * 128);
#pragma unroll
        for (int mt = 0; mt < 4; ++mt)
          acc[mt][nt] = __builtin_amdgcn_mfma_f32_16x16x32_bf16(
              af[mt], bf, acc[mt][nt], 0, 0, 0);
      }
    }
    if (c8 < 3) {
      unsigned short* Db = As2 + ((c8 + 1) & 1) * BUFN;
      *(short8*)(Db + dof0) = n0;
      *(short8*)(Db + dof1) = n1;
      if (sv2) *(short8*)(Db + dof2) = n2;
    }
    __syncthreads();
  }

  // epilogue: +bias, write bf16 pixel-major Y[b][oy*128+ox][co]
  const int oy = 2 * sy + py;
  unsigned short* Yb = Y + ((size_t)b * 16384 + (size_t)oy * 128 + px) * 256;
  float bco[4];
#pragma unroll
  for (int nt = 0; nt < 4; ++nt) bco[nt] = bt[co_w + nt * 16 + lr];
#pragma unroll
  for (int mt = 0; mt < 4; ++mt) {
#pragma unroll
    for (int r = 0; r < 4; ++r) {
      const int sx = mt * 16 + lg * 4 + r;
      unsigned short* yp = Yb + (size_t)(2 * sx) * 256 + co_w + lr;
#pragma unroll
      for (int nt = 0; nt < 4; ++nt)
        yp[nt * 16] = f2bf(acc[mt][nt][r] + bco[nt]);
    }
  }
}

// ---------------- instance-norm stats over pixel-major Y ----------------
__global__ __launch_bounds__(256) void inorm_stats_kernel(
    const unsigned short* __restrict__ Y, float* __restrict__ ssum,
    float* __restrict__ ssq) {
  const int b = blockIdx.y, sl = blockIdx.x, c = threadIdx.x;
  const unsigned short* p = Y + ((size_t)b * 16384 + (size_t)sl * 1024) * 256 + c;
  float s = 0.f, q = 0.f;
  for (int i = 0; i < 1024; ++i) {
    const float v = bf2f(p[(size_t)i * 256]);
    s += v;
    q += v * v;
  }
  atomicAdd(&ssum[b * 256 + c], s);
  atomicAdd(&ssq[b * 256 + c], q);
}

// ------- apply IN + LReLU to Y, write bf16 into Xpad interior -------
__global__ __launch_bounds__(256) void inorm_apply_kernel(
    const unsigned short* __restrict__ Y, const float* __restrict__ ssum,
    const float* __restrict__ ssq, unsigned short* __restrict__ Xpad) {
  const int b = blockIdx.y, sl = blockIdx.x, c = threadIdx.x;
  const float m = ssum[b * 256 + c] * (1.f / 16384.f);
  float var = ssq[b * 256 + c] * (1.f / 16384.f) - m * m;
  var = var < 0.f ? 0.f : var;
  const float r = rsqrtf(var + 1e-5f);
  const unsigned short* p = Y + ((size_t)b * 16384 + (size_t)sl * 1024) * 256 + c;
  unsigned short* dst = Xpad + (size_t)b * 130 * 130 * 256 + c;
  for (int i = 0; i < 1024; ++i) {
    const int pix = sl * 1024 + i;
    const int yy = pix >> 7, xx = pix & 127;
    float v = bf2f(p[(size_t)i * 256]);
    v = (v - m) * r;
    v = v >= 0.f ? v : 0.2f * v;
    dst[((size_t)(yy + 1) * 130 + (xx + 1)) * 256] = f2bf(v);
  }
}

// ---------------- reflect borders of Xpad: rows then cols ----------------
__global__ __launch_bounds__(256) void pad_rows_kernel(unsigned short* __restrict__ Xp) {
  const int b = blockIdx.x >> 1, side = blockIdx.x & 1;
  unsigned short* Xb = Xp + (size_t)b * 130 * 130 * 256;
  const int dr = side ? 129 : 0, sr = side ? 127 : 2;
  for (int i = threadIdx.x; i < 4096; i += 256) {
    const int c = 1 + (i >> 5), o = (i & 31) * 8;
    *(short8*)(Xb + ((size_t)dr * 130 + c) * 256 + o) =
        *(const short8*)(Xb + ((size_t)sr * 130 + c) * 256 + o);
  }
}
__global__ __launch_bounds__(256) void pad_cols_kernel(unsigned short* __restrict__ Xp) {
  const int b = blockIdx.x >> 1, side = blockIdx.x & 1;
  unsigned short* Xb = Xp + (size_t)b * 130 * 130 * 256;
  const int dc = side ? 129 : 0, sc = side ? 127 : 2;
  for (int i = threadIdx.x; i < 130 * 32; i += 256) {
    const int r = i >> 5, o = (i & 31) * 8;
    *(short8*)(Xb + ((size_t)r * 130 + dc) * 256 + o) =
        *(const short8*)(Xb + ((size_t)r * 130 + sc) * 256 + o);
  }
}

// ------ weight repack: w3 [512][256][9] fp32 -> Wb [9][512][256] bf16 ------
__global__ __launch_bounds__(256) void wprep_kernel(const float* __restrict__ w3,
                                                    unsigned short* __restrict__ Wb) {
  const int i = blockIdx.x * 256 + threadIdx.x;
  if (i >= 9 * 512 * 256) return;
  const int ci = i & 255, co = (i >> 8) & 511, tap = i >> 17;
  Wb[i] = f2bf(w3[((size_t)co * 256 + ci) * 9 + tap]);
}

// ---------------- label extraction + counts from one-hot segmap ----------------
__global__ __launch_bounds__(256) void label_kernel(
    const float* __restrict__ segmap, int* __restrict__ labels,
    float* __restrict__ cnt) {
  const int b = blockIdx.y;
  const int p = blockIdx.x * 256 + threadIdx.x;
  const int i = p >> 7, j = p & 127;
  const float* sp = segmap + (size_t)b * 19 * 65536 + (2 * i) * 256 + 2 * j;
  int lab = 0;
#pragma unroll
  for (int s = 0; s < 19; ++s)
    if (sp[(size_t)s * 65536] != 0.f) lab = s;
  labels[b * 16384 + p] = lab;
  atomicAdd(&cnt[b * 19 + lab], 1.0f);
}

// ---------------- conv3: bf16 MFMA implicit GEMM + tanh + region pool --------
__global__ __launch_bounds__(256, 3) void conv3_mfma_pool_kernel(
    const unsigned short* __restrict__ Xpad, const unsigned short* __restrict__ Wb,
    const float* __restrict__ bias, const int* __restrict__ labels,
    float* __restrict__ sums) {
  const int raw = blockIdx.x;
  const int swz = (raw & 7) * 512 + (raw >> 3);
  const int b = swz >> 9;
  const int rem = swz & 511;
  const int strip = rem >> 1;
  const int coh = rem & 1;
  const int y = strip >> 1;
  const int x0 = (strip & 1) * 64;

  constexpr int RS = 40;
  constexpr int BUFN = 3 * 66 * RS;
  __shared__ unsigned short Asw[2 * BUFN];
  __shared__ float lsum[19 * 256];

  const int t = threadIdx.x;
  const int lane = t & 63;
  const int wn = t >> 6;
  const int lg = lane >> 4, lr = lane & 15;
  const int co_w = coh * 256 + wn * 64;

  for (int i = t; i < 19 * 256; i += 256) lsum[i] = 0.f;

  const unsigned short* Xb = Xpad + (size_t)b * 130 * 130 * 256;

  int dof0, dof1, dof2, dof3;
  const unsigned short *sp0, *sp1, *sp2, *sp3;
  bool sv3;
  {
    const int i0 = t, i1 = t + 256, i2 = t + 512, i3 = t + 768;
    const int r0 = i0 / 264, c0 = (i0 % 264) >> 2, h0 = i0 & 3;
    const int r1 = i1 / 264, c1 = (i1 % 264) >> 2, h1 = i1 & 3;
    const int r2 = i2 / 264, c2 = (i2 % 264) >> 2, h2 = i2 & 3;
    sv3 = i3 < 792;
    const int i3c = sv3 ? i3 : 768;
    const int r3 = i3c / 264, c3 = (i3c % 264) >> 2, h3 = i3c & 3;
    dof0 = (r0 * 66 + c0) * RS + h0 * 8;
    dof1 = (r1 * 66 + c1) * RS + h1 * 8;
    dof2 = (r2 * 66 + c2) * RS + h2 * 8;
    dof3 = (r3 * 66 + c3) * RS + h3 * 8;
    sp0 = Xb + ((size_t)(y + r0) * 130 + x0 + c0) * 256 + h0 * 8;
    sp1 = Xb + ((size_t)(y + r1) * 130 + x0 + c1) * 256 + h1 * 8;
    sp2 = Xb + ((size_t)(y + r2) * 130 + x0 + c2) * 256 + h2 * 8;
    sp3 = Xb + ((size_t)(y + r3) * 130 + x0 + c3) * 256 + h3 * 8;
  }

  f32x4 acc[4][4];
#pragma unroll
  for (int mt = 0; mt < 4; ++mt)
#pragma unroll
    for (int nt = 0; nt < 4; ++nt) {
      f32x4 z = {0.f, 0.f, 0.f, 0.f};
      acc[mt][nt] = z;
    }

  {
    const short8 a = *(const short8*)sp0;
    const short8 bq = *(const short8*)sp1;
    const short8 cq = *(const short8*)sp2;
    short8 dq;
    if (sv3) dq = *(const short8*)sp3;
    *(short8*)(Asw + dof0) = a;
    *(short8*)(Asw + dof1) = bq;
    *(short8*)(Asw + dof2) = cq;
    if (sv3) *(short8*)(Asw + dof3) = dq;
  }
  __syncthreads();

  for (int c8 = 0; c8 < 8; ++c8) {
    short8 n0, n1, n2, n3;
    if (c8 < 7) {
      const int cn = (c8 + 1) * 32;
      n0 = *(const short8*)(sp0 + cn);
      n1 = *(const short8*)(sp1 + cn);
      n2 = *(const short8*)(sp2 + cn);
      if (sv3) n3 = *(const short8*)(sp3 + cn);
    }
    const unsigned short* Ab = Asw + (c8 & 1) * BUFN;
#pragma unroll
    for (int ky = 0; ky < 3; ++ky) {
#pragma unroll
      for (int kx = 0; kx < 3; ++kx) {
        short8 af[4];
#pragma unroll
        for (int mt = 0; mt < 4; ++mt) {
          const int px = mt * 16 + lr + kx;
          af[mt] = *(const short8*)(Ab + (ky * 66 + px) * RS + lg * 8);
        }
        const unsigned short* wt_ =
            Wb + (size_t)((ky * 3 + kx) * 512 + co_w + lr) * 256 + c8 * 32 + lg * 8;
#pragma unroll
        for (int nt = 0; nt < 4; ++nt) {
          const short8 bf = *(const short8*)(wt_ + nt * 16 * 256);
#pragma unroll
          for (int mt = 0; mt < 4; ++mt)
            acc[mt][nt] = __builtin_amdgcn_mfma_f32_16x16x32_bf16(
                af[mt], bf, acc[mt][nt], 0, 0, 0);
        }
      }
    }
    if (c8 < 7) {
      unsigned short* Db = Asw + ((c8 + 1) & 1) * BUFN;
      *(short8*)(Db + dof0) = n0;
      *(short8*)(Db + dof1) = n1;
      *(short8*)(Db + dof2) = n2;
      if (sv3) *(short8*)(Db + dof3) = n3;
    }
    __syncthreads();
  }

  const int* labp = labels + b * 16384 + y * 128 + x0;
  float bco[4];
#pragma unroll
  for (int nt = 0; nt < 4; ++nt) bco[nt] = bias[co_w + nt * 16 + lr];
#pragma unroll
  for (int mt = 0; mt < 4; ++mt) {
#pragma unroll
    for (int r = 0; r < 4; ++r) {
      const int lab = labp[mt * 16 + lg * 4 + r];
#pragma unroll
      for (int nt = 0; nt < 4; ++nt) {
        const float v = tanh_fast(acc[mt][nt][r] + bco[nt]);
        atomicAdd(&lsum[lab * 256 + wn * 64 + nt * 16 + lr], v);
      }
    }
  }
  __syncthreads();
  for (int i = t; i < 19 * 256; i += 256) {
    const float v = lsum[i];
    if (v != 0.f) {
      const int sI = i >> 8, c = i & 255;
      atomicAdd(&sums[((size_t)b * 19 + sI) * 512 + coh * 256 + c], v);
    }
  }
}

// ---------------- finalize: out = cnt>0 ? sums/max(cnt,1) : 0 ----------------
__global__ __launch_bounds__(256) void finalize_kernel(
    const float* __restrict__ sums, const float* __restrict__ cnt,
    float* __restrict__ out) {
  const int i = blockIdx.x * 256 + threadIdx.x;
  if (i >= B * 19 * 512) return;
  const int bs = i >> 9;
  const float c = cnt[bs];
  out[i] = c > 0.f ? sums[i] / fmaxf(c, 1.f) : 0.f;
}

// ---------------------------------------------------------------------------
extern "C" void kernel_launch(void* const* d_in, const int* in_sizes, int n_in,
                              void* d_out, int out_size, void* d_ws,
                              size_t ws_size, hipStream_t stream) {
  const float* input = (const float*)d_in[0];
  const float* segmap = (const float*)d_in[1];
  const float* w0 = (const float*)d_in[2];
  const float* b0 = (const float*)d_in[3];
  const float* w1 = (const float*)d_in[4];
  const float* b1 = (const float*)d_in[5];
  const float* w2 = (const float*)d_in[6];
  const float* b2 = (const float*)d_in[7];
  const float* wt = (const float*)d_in[8];
  const float* bt = (const float*)d_in[9];
  const float* w3 = (const float*)d_in[10];
  const float* b3 = (const float*)d_in[11];
  float* out = (float*)d_out;

  float* ws = (float*)d_ws;
  float* x0 = ws;                                    // 16,777,216 f
  float* x1 = x0 + 16777216;                         //  8,388,608 f
  float* x2 = x1 + 8388608;                          //  4,194,304 f
  unsigned short* X2p = (unsigned short*)(x2 + 4194304);  // 4,326,400 us
  unsigned short* Y = X2p + 4326400;                 // 33,554,432 us
  float* sums = (float*)(Y + 33554432);              //     77,824 f
  float* cnt = sums + 77824;                         //        152 f
  float* ssum = cnt + 152;                           //      2,048 f
  float* ssq = ssum + 2048;                          //      2,048 f
  int* labels = (int*)(ssq + 2048);                  //    131,072 i
  unsigned short* Wb = (unsigned short*)(labels + 131072);  // 1,179,648 us
  unsigned short* Wtb = Wb + 1179648;                //    294,912 us
  // Xpad bf16 [8][130][130][256] = 34,611,200 us = 69.2MB over x0+x1 (dead)
  unsigned short* Xpad = (unsigned short*)ws;

  hipMemsetAsync(sums, 0, (77824 + 152 + 2048 + 2048) * sizeof(float), stream);

  wprep_kernel<<<dim3((9 * 512 * 256 + 255) / 256), 256, 0, stream>>>(w3, Wb);
  wtprep_kernel<<<dim3((9 * 256 * 128 + 255) / 256), 256, 0, stream>>>(wt, Wtb);
  conv0_kernel<<<dim3(256, B), 256, 0, stream>>>(input, w0, b0, x0);
  inorm_lrelu_kernel<<<dim3(B * 32), 256, 0, stream>>>(x0, 65536);
  conv_s2_kernel<32, 64, 256><<<dim3(64, 2, B), 256, 0, stream>>>(x0, w1, b1, x1);
  inorm_lrelu_kernel<<<dim3(B * 64), 256, 0, stream>>>(x1, 16384);
  conv_s2_kernel<64, 128, 128><<<dim3(16, 4, B), 256, 0, stream>>>(x1, w2, b2, x2);
  inorm_lrelu_kernel<<<dim3(B * 128), 256, 0, stream>>>(x2, 4096);
  transpose_x2_kernel<<<dim3(128, B), 256, 0, stream>>>(x2, X2p);
  zpad_x2_kernel<<<dim3(B), 256, 0, stream>>>(X2p);
  convt_mfma_kernel<<<dim3(2048), 256, 0, stream>>>(X2p, Wtb, bt, Y);
  inorm_stats_kernel<<<dim3(16, B), 256, 0, stream>>>(Y, ssum, ssq);
  inorm_apply_kernel<<<dim3(16, B), 256, 0, stream>>>(Y, ssum, ssq, Xpad);
  pad_rows_kernel<<<dim3(2 * B), 256, 0, stream>>>(Xpad);
  pad_cols_kernel<<<dim3(2 * B), 256, 0, stream>>>(Xpad);
  label_kernel<<<dim3(64, B), 256, 0, stream>>>(segmap, labels, cnt);
  conv3_mfma_pool_kernel<<<dim3(4096), 256, 0, stream>>>(Xpad, Wb, b3, labels, sums);
  finalize_kernel<<<dim3((B * 19 * 512 + 255) / 256), 256, 0, stream>>>(sums, cnt, out);
}